// Round 5
// baseline (207.299 us; speedup 1.0000x reference)
//
#include <hip/hip_runtime.h>
#include <math.h>

// loss = mean_b[ 0.5*nrmse(o1,t1) + 0.25*nrmse(o2,t2) + 0.25*nrmse(o3,t3) ]
// B=4096 rows, N=2048 fp32/row, 192 MiB read. R2-R4 all pinned at 73.7 us
// (2.73 TB/s) regardless of per-wave MLP / occupancy -> per-CU miss-queue x
// latency product is the wall. This version attacks LATENCY via DRAM
// locality: copy-kernel-style chip-wide sequential sweep (all waves advance
// through each array together in contiguous 8 MiB windows) instead of ~4000
// scattered 8 KiB row streams. Per-1KiB-chunk partials go to ws; stage 2
// recombines chunks into per-row nrmse.
constexpr int N_ELEM   = 2048;
constexpr int BATCH    = 4096;
constexpr int BLOCK    = 256;
constexpr int GRID1    = 2048;                        // 8 blocks/CU -> 32 waves/CU
constexpr int NTHREADS = GRID1 * BLOCK;               // 524288
constexpr int F4_PAIR  = BATCH * N_ELEM / 4;          // 2,097,152 float4 per array
constexpr int ROUNDS   = F4_PAIR / NTHREADS;          // 4 sweep rounds per pair
constexpr int WAVES1   = NTHREADS / 64;               // 8192
constexpr int CH_PAIR  = F4_PAIR / 64;                // 32768 chunks per pair
constexpr int ROWS     = 3 * BATCH;                   // 12288
constexpr int GRID2    = ROWS / BLOCK;                // 48

// Stage 1: chip-wide sweep. One wave-load = one 1 KiB chunk (64 lanes x
// float4), chunk-uniform row. Per chunk: wave-reduce ssd/max/min, lane 0
// stores the triple to ws. Consecutive waves read consecutive chunks, so the
// whole chip's in-flight window is a few dense MiB -> DRAM row-buffer hits.
__global__ __launch_bounds__(BLOCK)
void wnrmse_stage1(const float* __restrict__ o1, const float* __restrict__ t1,
                   const float* __restrict__ o2, const float* __restrict__ t2,
                   const float* __restrict__ o3, const float* __restrict__ t3,
                   float* __restrict__ ssd_ws, float* __restrict__ max_ws,
                   float* __restrict__ min_ws)
{
    const int g    = blockIdx.x * BLOCK + threadIdx.x;   // global thread
    const int lane = threadIdx.x & 63;
    const int gw   = g >> 6;                             // global wave 0..8191

    const float* const os[3] = { o1, o2, o3 };
    const float* const ts[3] = { t1, t2, t3 };

#pragma unroll
    for (int p = 0; p < 3; ++p) {
        const float4* o4 = (const float4*)os[p];
        const float4* t4 = (const float4*)ts[p];
#pragma unroll
        for (int j = 0; j < ROUNDS; ++j) {
            const int idx = g + j * NTHREADS;            // float4 index
            float4 ov = o4[idx];
            float4 tv = t4[idx];

            float d0 = ov.x - tv.x, d1 = ov.y - tv.y;
            float d2 = ov.z - tv.z, d3 = ov.w - tv.w;
            float ssd = d0 * d0 + d1 * d1 + d2 * d2 + d3 * d3;
            float mx = fmaxf(fmaxf(tv.x, tv.y), fmaxf(tv.z, tv.w));
            float mn = fminf(fminf(tv.x, tv.y), fminf(tv.z, tv.w));

#pragma unroll
            for (int off = 32; off > 0; off >>= 1) {
                ssd += __shfl_xor(ssd, off, 64);
                mx   = fmaxf(mx, __shfl_xor(mx, off, 64));
                mn   = fminf(mn, __shfl_xor(mn, off, 64));
            }

            if (lane == 0) {
                // chunk id within pair: float4 start = 64*(gw + j*8192)
                const int c = p * CH_PAIR + gw + j * WAVES1;
                ssd_ws[c] = ssd;
                max_ws[c] = mx;
                min_ws[c] = mn;
            }
        }
    }
}

// Stage 2: one thread per row. Row r of pair p owns chunks
// [p*CH_PAIR + row*8, +8). Combine, nrmse, weight, block-reduce, atomic.
__global__ __launch_bounds__(BLOCK)
void wnrmse_stage2(const float* __restrict__ ssd_ws, const float* __restrict__ max_ws,
                   const float* __restrict__ min_ws, float* __restrict__ out)
{
    const int r   = blockIdx.x * BLOCK + threadIdx.x;    // 0..12287
    const int p   = r >> 12;                             // r / 4096
    const int row = r & (BATCH - 1);
    const int base = p * CH_PAIR + row * 8;

    float ssd = 0.f, mx = -INFINITY, mn = INFINITY;
#pragma unroll
    for (int k = 0; k < 8; ++k) {
        ssd += ssd_ws[base + k];
        mx   = fmaxf(mx, max_ws[base + k]);
        mn   = fminf(mn, min_ws[base + k]);
    }
    const float w = (p == 0) ? 0.50f : 0.25f;
    float val = w * sqrtf(ssd * (1.0f / (float)N_ELEM)) / (mx - mn);

#pragma unroll
    for (int off = 32; off > 0; off >>= 1) val += __shfl_xor(val, off, 64);

    __shared__ float s_part[BLOCK / 64];
    const int wave = threadIdx.x >> 6;
    const int lane = threadIdx.x & 63;
    if (lane == 0) s_part[wave] = val;
    __syncthreads();
    if (threadIdx.x == 0) {
        float blk = s_part[0] + s_part[1] + s_part[2] + s_part[3];
        atomicAdd(out, blk * (1.0f / (float)BATCH));   // 48 atomics total
    }
}

extern "C" void kernel_launch(void* const* d_in, const int* in_sizes, int n_in,
                              void* d_out, int out_size, void* d_ws, size_t ws_size,
                              hipStream_t stream) {
    const float* o1 = (const float*)d_in[0];
    const float* t1 = (const float*)d_in[1];
    const float* o2 = (const float*)d_in[2];
    const float* t2 = (const float*)d_in[3];
    const float* o3 = (const float*)d_in[4];
    const float* t3 = (const float*)d_in[5];
    float* out = (float*)d_out;

    float* ssd_ws = (float*)d_ws;                 // 3*32768 floats
    float* max_ws = ssd_ws + 3 * CH_PAIR;
    float* min_ws = max_ws + 3 * CH_PAIR;         // total 1.18 MB of ws

    hipMemsetAsync(out, 0, sizeof(float), stream);
    wnrmse_stage1<<<GRID1, BLOCK, 0, stream>>>(o1, t1, o2, t2, o3, t3,
                                               ssd_ws, max_ws, min_ws);
    wnrmse_stage2<<<GRID2, BLOCK, 0, stream>>>(ssd_ws, max_ws, min_ws, out);
}